// Round 3
// baseline (257.891 us; speedup 1.0000x reference)
//
#include <hip/hip_runtime.h>
#include <math.h>

// B=2, N=131072 (=2^17), K=9, P=4, D=4, S=1, CI=8, CO=8
#define N_PTS 131072
#define KNB   9
#define PD    16
#define CIN   8
#define COUT  8
#define PTS_PER_BLK 64        // 4 points per thread
#define PTS_PER_THREAD 4
#define THREADS 256
#define AMP_STRIDE 68         // 64 + 4 pad: pd-lanes 4 banks apart -> 2-way (free)

// Native clang vector types (accepted by __builtin_nontemporal_*)
typedef float vf4 __attribute__((ext_vector_type(4)));
typedef int   vi4 __attribute__((ext_vector_type(4)));

__global__ __launch_bounds__(THREADS) void polnormal_kernel(
    const float* __restrict__ x,      // (B, N, CI)
    const float* __restrict__ dx,     // (B, N, K)
    const float* __restrict__ dy,     // (B, N, K)
    const int*   __restrict__ adj,    // (N, K)
    const float* __restrict__ phis,   // (P,)
    const float* __restrict__ dists,  // (D,)
    const float* __restrict__ sigma,  // (S,)
    const float* __restrict__ amp,    // (P, D, S, CI, CO)
    float*       __restrict__ out)    // (B, N, P, D, S, CO)
{
    __shared__ float s_dx[PTS_PER_BLK * KNB];            // 2304 B
    __shared__ float s_dy[PTS_PER_BLK * KNB];            // 2304 B
    __shared__ int   s_adj[PTS_PER_BLK * KNB];           // 2304 B
    __shared__ float s_x[PTS_PER_BLK * KNB * CIN];       // 18432 B
    __shared__ float s_amp[PD * AMP_STRIDE];             // 4352 B

    const int  tid    = threadIdx.x;
    const long base_g = (long)blockIdx.x * PTS_PER_BLK;  // 64 | N -> no batch straddle
    const int  b      = (int)(base_g >> 17);             // N = 2^17
    const int  base_n = (int)(base_g & (N_PTS - 1));

    // ---- Stage dx/dy/adj: 576 elems each = 144 vec4 loads (nontemporal, single-use streams)
    if (tid < (PTS_PER_BLK * KNB) / 4) {
        const vf4* pdx = (const vf4*)(dx + base_g * KNB);
        const vf4* pdy = (const vf4*)(dy + base_g * KNB);
        const vi4* pad = (const vi4*)(adj + (long)base_n * KNB);
        ((vf4*)s_dx)[tid] = __builtin_nontemporal_load(pdx + tid);
        ((vf4*)s_dy)[tid] = __builtin_nontemporal_load(pdy + tid);
        ((vi4*)s_adj)[tid] = __builtin_nontemporal_load(pad + tid);
    }
    // ---- Stage amplitudes with padding: flat = pd*64 + c*8 + o
    for (int t = tid; t < PD * CIN * COUT; t += THREADS) {
        int pd = t >> 6;
        int co = t & 63;
        s_amp[pd * AMP_STRIDE + co] = amp[t];
    }
    __syncthreads();   // s_adj ready

    // ---- Gather neighbor features: 576 rows x 32 B = 1152 float4 loads (kept cacheable)
    {
        const vf4* xb = (const vf4*)x + (long)b * N_PTS * 2;
        for (int t = tid; t < PTS_PER_BLK * KNB * 2; t += THREADS) {
            int pair = t >> 1;
            int half = t & 1;
            ((vf4*)s_x)[t] = xb[(long)s_adj[pair] * 2 + half];
        }
    }
    __syncthreads();

    // ---- Compute: thread owns (i0 + 16j, pd) for j = 0..3
    const int i0 = tid >> 4;
    const int pd = tid & 15;
    const int p  = pd >> 2;
    const int d  = pd & 3;

    const float phi  = phis[p];
    const float dist = dists[d];
    float sn, cs;
    __sincosf(phi, &sn, &cs);
    const float mux = cs * dist;
    const float muy = sn * dist;

    const float sig        = fmaxf(sigma[0], 1e-10f);
    const float s2         = sig * sig;
    const float neg_inv2s2 = -0.5f / s2;
    const float norm       = rsqrtf(6.283185307179586f * s2);

    float wx[PTS_PER_THREAD][CIN];
#pragma unroll
    for (int j = 0; j < PTS_PER_THREAD; ++j)
#pragma unroll
        for (int c = 0; c < CIN; ++c) wx[j][c] = 0.0f;

#pragma unroll
    for (int k = 0; k < KNB; ++k) {
#pragma unroll
        for (int j = 0; j < PTS_PER_THREAD; ++j) {
            const int i   = i0 + 16 * j;
            const int ik  = i * KNB + k;
            float ddx = s_dx[ik] - mux;
            float ddy = s_dy[ik] - muy;
            float r2  = ddx * ddx + ddy * ddy;
            float w   = __expf(neg_inv2s2 * r2) * norm;
            const vf4* xr = (const vf4*)&s_x[ik * CIN];
            vf4 x0 = xr[0], x1 = xr[1];
            wx[j][0] += w * x0.x; wx[j][1] += w * x0.y;
            wx[j][2] += w * x0.z; wx[j][3] += w * x0.w;
            wx[j][4] += w * x1.x; wx[j][5] += w * x1.y;
            wx[j][6] += w * x1.z; wx[j][7] += w * x1.w;
        }
    }

    float acc[PTS_PER_THREAD][COUT];
#pragma unroll
    for (int j = 0; j < PTS_PER_THREAD; ++j)
#pragma unroll
        for (int o = 0; o < COUT; ++o) acc[j][o] = 0.0f;

#pragma unroll
    for (int c = 0; c < CIN; ++c) {
        const vf4* ar = (const vf4*)&s_amp[pd * AMP_STRIDE + c * COUT];
        vf4 a0 = ar[0], a1 = ar[1];
#pragma unroll
        for (int j = 0; j < PTS_PER_THREAD; ++j) {
            const float wc = wx[j][c];
            acc[j][0] += wc * a0.x; acc[j][1] += wc * a0.y;
            acc[j][2] += wc * a0.z; acc[j][3] += wc * a0.w;
            acc[j][4] += wc * a1.x; acc[j][5] += wc * a1.y;
            acc[j][6] += wc * a1.z; acc[j][7] += wc * a1.w;
        }
    }

    // ---- Store: nontemporal (write-once stream; don't evict gather-hot x from L2)
#pragma unroll
    for (int j = 0; j < PTS_PER_THREAD; ++j) {
        const int i = i0 + 16 * j;
        vf4* op = (vf4*)(out + ((base_g + i) * PD + pd) * COUT);
        vf4 lo = {acc[j][0], acc[j][1], acc[j][2], acc[j][3]};
        vf4 hi = {acc[j][4], acc[j][5], acc[j][6], acc[j][7]};
        __builtin_nontemporal_store(lo, op);
        __builtin_nontemporal_store(hi, op + 1);
    }
}

extern "C" void kernel_launch(void* const* d_in, const int* in_sizes, int n_in,
                              void* d_out, int out_size, void* d_ws, size_t ws_size,
                              hipStream_t stream) {
    const float* x     = (const float*)d_in[0];
    const float* dx    = (const float*)d_in[1];
    const float* dy    = (const float*)d_in[2];
    const int*   adj   = (const int*)  d_in[3];
    const float* phis  = (const float*)d_in[4];
    const float* dists = (const float*)d_in[5];
    const float* sigma = (const float*)d_in[6];
    const float* amp   = (const float*)d_in[7];
    float* out = (float*)d_out;

    const int total_pts = 2 * N_PTS;                 // 262144
    const int grid = total_pts / PTS_PER_BLK;        // 4096 blocks
    polnormal_kernel<<<grid, THREADS, 0, stream>>>(x, dx, dy, adj, phis, dists,
                                                   sigma, amp, out);
}

// Round 4
// 213.076 us; speedup vs baseline: 1.2103x; 1.2103x over previous
//
#include <hip/hip_runtime.h>
#include <math.h>

// B=2, N=131072 (=2^17), K=9, P=4, D=4, S=1, CI=8, CO=8
#define N_PTS 131072
#define KNB   9
#define PD    16
#define CIN   8
#define COUT  8
#define PTS_PER_BLK 16        // 1 point per thread-group-of-16, 1 pt/thread cell
#define THREADS 256
#define AMP_STRIDE 68         // 64 + 4 pad: pd-lanes 4 banks apart -> 2-way (free)

typedef float vf2 __attribute__((ext_vector_type(2)));
typedef float vf4 __attribute__((ext_vector_type(4)));
typedef int   vi4 __attribute__((ext_vector_type(4)));

__global__ __launch_bounds__(THREADS) void polnormal_kernel(
    const float* __restrict__ x,      // (B, N, CI)
    const float* __restrict__ dx,     // (B, N, K)
    const float* __restrict__ dy,     // (B, N, K)
    const int*   __restrict__ adj,    // (N, K)
    const float* __restrict__ phis,   // (P,)
    const float* __restrict__ dists,  // (D,)
    const float* __restrict__ sigma,  // (S,)
    const float* __restrict__ amp,    // (P, D, S, CI, CO)
    float*       __restrict__ out)    // (B, N, P, D, S, CO)
{
    __shared__ float s_dx[PTS_PER_BLK * KNB];        // 576 B
    __shared__ float s_dy[PTS_PER_BLK * KNB];        // 576 B
    __shared__ int   s_adj[PTS_PER_BLK * KNB];       // 576 B
    __shared__ float s_amp[PD * AMP_STRIDE];         // 4352 B

    const int  tid    = threadIdx.x;
    const long base_g = (long)blockIdx.x * PTS_PER_BLK;  // 16 | 2^17 -> no batch straddle
    const int  b      = (int)(base_g >> 17);
    const int  base_n = (int)(base_g & (N_PTS - 1));

    // ---- Stage dx/dy/adj (144 elems each = 36 vec4, coalesced) + amp (1024 floats)
    if (tid < (PTS_PER_BLK * KNB) / 4) {             // 36 threads
        const vf4* pdx = (const vf4*)(dx + base_g * KNB);
        const vf4* pdy = (const vf4*)(dy + base_g * KNB);
        const vi4* pad = (const vi4*)(adj + (long)base_n * KNB);
        ((vf4*)s_dx)[tid]  = pdx[tid];
        ((vf4*)s_dy)[tid]  = pdy[tid];
        ((vi4*)s_adj)[tid] = pad[tid];
    }
    for (int t = tid; t < PD * CIN * COUT; t += THREADS) {
        int pdi = t >> 6;
        int co  = t & 63;
        s_amp[pdi * AMP_STRIDE + co] = amp[t];
    }

    // ---- Per-thread uniforms (overlap with staging, before the barrier)
    const int i  = tid >> 4;       // point within block
    const int pd = tid & 15;
    const int p  = pd >> 2;
    const int d  = pd & 3;

    const float phi  = phis[p];
    const float dist = dists[d];
    float sn, cs;
    __sincosf(phi, &sn, &cs);
    const float mux = cs * dist;
    const float muy = sn * dist;

    const float sig   = fmaxf(sigma[0], 1e-10f);
    const float s2    = sig * sig;
    const float k2    = (-0.5f / s2) * 1.4426950408889634f;   // exp(a) = exp2(a*log2e)
    const float norm  = rsqrtf(6.283185307179586f * s2);

    __syncthreads();   // LDS ready; the ONLY barrier — x-gather below is barrier-free

    // ---- k-loop: gather x row directly from global (L2/LLC), packed accumulate wx
    const vf4* xb = (const vf4*)x + (long)b * N_PTS * 2;

    vf2 wx01 = {0.f, 0.f}, wx23 = {0.f, 0.f}, wx45 = {0.f, 0.f}, wx67 = {0.f, 0.f};

#pragma unroll
    for (int k = 0; k < KNB; ++k) {
        const int ik = i * KNB + k;
        const long row = (long)s_adj[ik];
        vf4 x0 = xb[row * 2];
        vf4 x1 = xb[row * 2 + 1];
        float ddx = s_dx[ik] - mux;
        float ddy = s_dy[ik] - muy;
        float r2  = __builtin_fmaf(ddx, ddx, ddy * ddy);
        float w   = __builtin_amdgcn_exp2f(k2 * r2) * norm;
        wx01 += w * x0.xy;
        wx23 += w * x0.zw;
        wx45 += w * x1.xy;
        wx67 += w * x1.zw;
    }

    // ---- c-loop: acc[o] += wx[c] * amp[pd][c][o], packed over o
    vf2 ac01 = {0.f, 0.f}, ac23 = {0.f, 0.f}, ac45 = {0.f, 0.f}, ac67 = {0.f, 0.f};
    const float wxs[CIN] = {wx01.x, wx01.y, wx23.x, wx23.y,
                            wx45.x, wx45.y, wx67.x, wx67.y};
#pragma unroll
    for (int c = 0; c < CIN; ++c) {
        const vf4* ar = (const vf4*)&s_amp[pd * AMP_STRIDE + c * COUT];
        vf4 a0 = ar[0], a1 = ar[1];
        const float wc = wxs[c];
        ac01 += wc * a0.xy;
        ac23 += wc * a0.zw;
        ac45 += wc * a1.xy;
        ac67 += wc * a1.zw;
    }

    // ---- Store: nontemporal write-once stream; contiguous across pd-lanes
    vf4* op = (vf4*)(out + ((base_g + i) * PD + pd) * COUT);
    vf4 lo = {ac01.x, ac01.y, ac23.x, ac23.y};
    vf4 hi = {ac45.x, ac45.y, ac67.x, ac67.y};
    __builtin_nontemporal_store(lo, op);
    __builtin_nontemporal_store(hi, op + 1);
}

extern "C" void kernel_launch(void* const* d_in, const int* in_sizes, int n_in,
                              void* d_out, int out_size, void* d_ws, size_t ws_size,
                              hipStream_t stream) {
    const float* x     = (const float*)d_in[0];
    const float* dx    = (const float*)d_in[1];
    const float* dy    = (const float*)d_in[2];
    const int*   adj   = (const int*)  d_in[3];
    const float* phis  = (const float*)d_in[4];
    const float* dists = (const float*)d_in[5];
    const float* sigma = (const float*)d_in[6];
    const float* amp   = (const float*)d_in[7];
    float* out = (float*)d_out;

    const int total_pts = 2 * N_PTS;                 // 262144
    const int grid = total_pts / PTS_PER_BLK;        // 16384 blocks
    polnormal_kernel<<<grid, THREADS, 0, stream>>>(x, dx, dy, adj, phis, dists,
                                                   sigma, amp, out);
}